// Round 1
// baseline (30.651 us; speedup 1.0000x reference)
//
#include <hip/hip_runtime.h>
#include <hip/hip_bf16.h>

// Problem constants (fixed by harness: H=W=128, C=64, K=3, HID=256, OUT_C=3, scale=2)
#define H_IN 128
#define W_IN 128
#define C_IN 64
#define HID 256
#define KW 3
#define OUT_C 3
#define OUT_H 256
#define OUT_W 256
#define NW (KW * KW * C_IN * OUT_C)  // 1728 weights per parity

// ---------------------------------------------------------------------------
// Kernel 1: h2[par][n] = relu( relu(V@k1+b1) @ k2 + b2 )   for 4 parities.
// Grid: 16 blocks (par = b>>2, col-chunk = b&3), 64 threads (one h2 column each).
// ---------------------------------------------------------------------------
__global__ __launch_bounds__(64) void mlp12_kernel(
    const float* __restrict__ k1, const float* __restrict__ b1,
    const float* __restrict__ k2, const float* __restrict__ b2,
    float* __restrict__ h2out)
{
    __shared__ float h1[HID];
    const int par   = blockIdx.x >> 2;
    const int chunk = blockIdx.x & 3;
    const float vi = 0.5f * (float)(par >> 1);
    const float vj = 0.5f * (float)(par & 1);
    const int tid = threadIdx.x;

    for (int n = tid; n < HID; n += 64) {
        float a = vi * k1[n] + vj * k1[HID + n] + 0.5f * k1[2 * HID + n] + b1[n];
        h1[n] = fmaxf(a, 0.0f);
    }
    __syncthreads();

    const int n = chunk * 64 + tid;   // 0..255
    float s = b2[n];
    for (int m = 0; m < HID; ++m)
        s = fmaf(h1[m], k2[m * HID + n], s);
    h2out[par * HID + n] = fmaxf(s, 0.0f);
}

// ---------------------------------------------------------------------------
// Kernel 2: w[par][n] = h2[par] @ k3 + b3, stored transposed as [par][o][pq][c].
// Grid: 27 blocks x 64 threads (each thread: one of the 1728 columns, 4 parities).
// k3 (1.77 MB) is streamed exactly once.
// ---------------------------------------------------------------------------
__global__ __launch_bounds__(64) void mlp3_kernel(
    const float* __restrict__ k3, const float* __restrict__ b3,
    const float* __restrict__ h2, float* __restrict__ wout)
{
    __shared__ float h[4][HID];
    const int tid = threadIdx.x;
    for (int m = tid; m < 4 * HID; m += 64)
        h[m >> 8][m & 255] = h2[m];
    __syncthreads();

    const int n = blockIdx.x * 64 + tid;   // 0..1727
    const float b = b3[n];
    float t0 = b, t1 = b, t2 = b, t3 = b;
    for (int m = 0; m < HID; ++m) {
        const float kv = k3[m * NW + n];
        t0 = fmaf(h[0][m], kv, t0);
        t1 = fmaf(h[1][m], kv, t1);
        t2 = fmaf(h[2][m], kv, t2);
        t3 = fmaf(h[3][m], kv, t3);
    }
    // n = ((p*3+q)*64 + c)*3 + o  ->  transposed index [o][pq][c]
    const int o = n % 3;
    const int rest = n / 3;
    const int c = rest & 63;
    const int pq = rest >> 6;
    const int base = (o * 9 + pq) * 64 + c;
    wout[0 * NW + base] = t0;
    wout[1 * NW + base] = t1;
    wout[2 * NW + base] = t2;
    wout[3 * NW + base] = t3;
}

// ---------------------------------------------------------------------------
// Kernel 3: the einsum. Wave = 4 parities x 16 c4-chunks; one input pixel per
// iteration (computes its whole 2x2 output quad). Weights register-stationary.
// Grid: 1024 blocks x 256 threads; wave handles a strip of 4 input pixels.
// ---------------------------------------------------------------------------
#define PPW 4   // input pixels per wave

__global__ __launch_bounds__(256) void upscale_kernel(
    const float* __restrict__ feat, const float* __restrict__ wts,
    float* __restrict__ out)
{
    const int lane = threadIdx.x & 63;
    const int wid  = threadIdx.x >> 6;                 // 0..3
    const int gw   = blockIdx.x * 4 + wid;             // 0..4095
    const int iy   = gw >> 5;                          // input row 0..127
    const int ix0  = (gw & 31) * PPW;                  // input col base
    const int par  = lane >> 4;                        // 0..3 (uniform per 16-lane group)
    const int c4   = lane & 15;                        // channel chunk 0..15
    const int pi = par >> 1, pj = par & 1;

    // Load 27 weight float4s for (par, c4): w[o][pq], register-stationary.
    float4 w[3][9];
#pragma unroll
    for (int o = 0; o < 3; ++o)
#pragma unroll
        for (int pq = 0; pq < 9; ++pq)
            w[o][pq] = *reinterpret_cast<const float4*>(
                wts + ((par * 3 + o) * 9 + pq) * 64 + c4 * 4);

    for (int g = 0; g < PPW; ++g) {
        const int ix = ix0 + g;
        float acc0 = 0.0f, acc1 = 0.0f, acc2 = 0.0f;
#pragma unroll
        for (int p = 0; p < 3; ++p) {
            const int r = iy + p - 1;
#pragma unroll
            for (int q = 0; q < 3; ++q) {
                const int cc = ix + q - 1;   // wave-uniform
                float4 f;
                if ((unsigned)r < (unsigned)H_IN && (unsigned)cc < (unsigned)W_IN) {
                    f = *reinterpret_cast<const float4*>(
                        feat + (r * W_IN + cc) * C_IN + c4 * 4);
                } else {
                    f = make_float4(0.0f, 0.0f, 0.0f, 0.0f);
                }
                const int pq = p * 3 + q;
                acc0 = fmaf(f.x, w[0][pq].x, acc0);
                acc0 = fmaf(f.y, w[0][pq].y, acc0);
                acc0 = fmaf(f.z, w[0][pq].z, acc0);
                acc0 = fmaf(f.w, w[0][pq].w, acc0);
                acc1 = fmaf(f.x, w[1][pq].x, acc1);
                acc1 = fmaf(f.y, w[1][pq].y, acc1);
                acc1 = fmaf(f.z, w[1][pq].z, acc1);
                acc1 = fmaf(f.w, w[1][pq].w, acc1);
                acc2 = fmaf(f.x, w[2][pq].x, acc2);
                acc2 = fmaf(f.y, w[2][pq].y, acc2);
                acc2 = fmaf(f.z, w[2][pq].z, acc2);
                acc2 = fmaf(f.w, w[2][pq].w, acc2);
            }
        }
        // Reduce over the 16 c4 lanes within each parity group.
#pragma unroll
        for (int m = 1; m <= 8; m <<= 1) {
            acc0 += __shfl_xor(acc0, m, 64);
            acc1 += __shfl_xor(acc1, m, 64);
            acc2 += __shfl_xor(acc2, m, 64);
        }
        if (c4 < 3) {
            const float v = (c4 == 0) ? acc0 : ((c4 == 1) ? acc1 : acc2);
            const int oy = 2 * iy + pi;
            const int ox = 2 * ix + pj;
            out[(oy * OUT_W + ox) * OUT_C + c4] = v;
        }
    }
}

// ---------------------------------------------------------------------------
extern "C" void kernel_launch(void* const* d_in, const int* in_sizes, int n_in,
                              void* d_out, int out_size, void* d_ws, size_t ws_size,
                              hipStream_t stream)
{
    const float* feat = (const float*)d_in[0];
    const float* k1   = (const float*)d_in[1];
    const float* b1   = (const float*)d_in[2];
    const float* k2   = (const float*)d_in[3];
    const float* b2   = (const float*)d_in[4];
    const float* k3   = (const float*)d_in[5];
    const float* b3   = (const float*)d_in[6];
    // d_in[7] = scale (int, ==2): baked into the kernels above.
    float* out = (float*)d_out;
    float* ws  = (float*)d_ws;
    float* wts = ws;            // 4*1728 floats, layout [par][o][pq][c]
    float* h2  = ws + 4 * NW;   // 4*256 floats

    mlp12_kernel<<<16, 64, 0, stream>>>(k1, b1, k2, b2, h2);
    mlp3_kernel<<<27, 64, 0, stream>>>(k3, b3, h2, wts);
    upscale_kernel<<<1024, 256, 0, stream>>>(feat, wts, out);
}

// Round 2
// 23.988 us; speedup vs baseline: 1.2778x; 1.2778x over previous
//
#include <hip/hip_runtime.h>
#include <hip/hip_bf16.h>

// Problem constants (fixed: H=W=128, C=64, K=3, HID=256, OUT_C=3, scale=2)
#define H_IN 128
#define W_IN 128
#define C_IN 64
#define HID 256
#define OUT_C 3
#define OUT_W 256
#define NW 1728   // 3*3*64*3 weights per parity

__device__ __forceinline__ float rdlane(float v, int l) {
    return __int_as_float(__builtin_amdgcn_readlane(__float_as_int(v), l));
}

// ---------------------------------------------------------------------------
// K1: partial h2 sums. Grid 16 blocks (par = b>>2, m-chunk = b&3) x 256 thr.
// part[par][mc][col] = sum_{m in chunk} h1[par][m] * k2[m][col]
// h1 lives in registers; wave-uniform operand fetched via v_readlane (no LDS
// in the hot loop). Bias/ReLU deferred to K2.
// ---------------------------------------------------------------------------
__global__ __launch_bounds__(256) void mlp12_kernel(
    const float* __restrict__ k1, const float* __restrict__ b1,
    const float* __restrict__ k2, float* __restrict__ part)
{
    __shared__ float sP[4][64][4];
    const int tid  = threadIdx.x;
    const int lane = tid & 63, w = tid >> 6;
    const int par  = blockIdx.x >> 2, mc = blockIdx.x & 3;
    const float vi = 0.5f * (float)(par >> 1);
    const float vj = 0.5f * (float)(par & 1);

    // h1[par][mc*64 + lane], replicated across the 4 waves
    const int m0 = mc * 64 + lane;
    const float hreg = fmaxf(vi * k1[m0] + vj * k1[HID + m0]
                             + 0.5f * k1[2 * HID + m0] + b1[m0], 0.0f);

    // wave w accumulates its 16-m slice for cols [4*lane, 4*lane+4)
    float4 acc = make_float4(0.f, 0.f, 0.f, 0.f);
    const int mbase = mc * 64 + w * 16;
#pragma unroll
    for (int i = 0; i < 16; ++i) {
        const float hm = rdlane(hreg, w * 16 + i);
        const float4 kv = *reinterpret_cast<const float4*>(
            k2 + (mbase + i) * HID + lane * 4);
        acc.x = fmaf(hm, kv.x, acc.x);
        acc.y = fmaf(hm, kv.y, acc.y);
        acc.z = fmaf(hm, kv.z, acc.z);
        acc.w = fmaf(hm, kv.w, acc.w);
    }
    *reinterpret_cast<float4*>(&sP[w][lane][0]) = acc;
    __syncthreads();

    const float s = sP[0][tid >> 2][tid & 3] + sP[1][tid >> 2][tid & 3]
                  + sP[2][tid >> 2][tid & 3] + sP[3][tid >> 2][tid & 3];
    part[(par * 4 + mc) * HID + tid] = s;
}

// ---------------------------------------------------------------------------
// K2: w = relu(h2) @ k3 + b3, transposed store. Grid 27 blocks x 256 thr.
// Wave w handles m in [64w, 64w+64) for the block's 64 columns; h2 rebuilt
// from partials into registers, broadcast via v_readlane. k3 read once.
// ---------------------------------------------------------------------------
__global__ __launch_bounds__(256) void mlp3_kernel(
    const float* __restrict__ k3, const float* __restrict__ b3,
    const float* __restrict__ b2, const float* __restrict__ part,
    float* __restrict__ wout)
{
    __shared__ float sR[4][4][64];
    const int tid  = threadIdx.x;
    const int lane = tid & 63, w = tid >> 6;
    const int colbase = blockIdx.x * 64;

    // h2[p][w*64 + lane] for p = 0..3
    const int mm = w * 64 + lane;
    float h2r[4];
#pragma unroll
    for (int p = 0; p < 4; ++p) {
        float s = b2[mm];
#pragma unroll
        for (int mc = 0; mc < 4; ++mc) s += part[(p * 4 + mc) * HID + mm];
        h2r[p] = fmaxf(s, 0.0f);
    }

    float a0 = 0.f, a1 = 0.f, a2 = 0.f, a3 = 0.f;
    const float* kp = k3 + (size_t)(w * 64) * NW + colbase + lane;
#pragma unroll
    for (int i = 0; i < 64; ++i) {
        const float kv = kp[(size_t)i * NW];
        a0 = fmaf(rdlane(h2r[0], i), kv, a0);
        a1 = fmaf(rdlane(h2r[1], i), kv, a1);
        a2 = fmaf(rdlane(h2r[2], i), kv, a2);
        a3 = fmaf(rdlane(h2r[3], i), kv, a3);
    }
    sR[w][0][lane] = a0; sR[w][1][lane] = a1;
    sR[w][2][lane] = a2; sR[w][3][lane] = a3;
    __syncthreads();

    const int p = tid >> 6, c = tid & 63;
    const int n = colbase + c;
    float s = b3[n] + sR[0][p][c] + sR[1][p][c] + sR[2][p][c] + sR[3][p][c];
    // n = ((pp*3+q)*64 + ch)*3 + o  ->  store [par][o][pq][ch]
    const int o = n % 3;
    const int rest = n / 3;
    const int cch = rest & 63;
    const int pq = rest >> 6;
    wout[p * NW + (o * 9 + pq) * 64 + cch] = s;
}

// ---------------------------------------------------------------------------
// K3: the einsum. Wave = 4 parities x 16 c4-chunks; PPW input pixels per wave
// (each yields its 2x2 output quad entry for this parity). Weights
// register-stationary (27 float4). Grid 512 x 256 = 2048 waves (2/SIMD).
// ---------------------------------------------------------------------------
#define PPW 8

__global__ __launch_bounds__(256) void upscale_kernel(
    const float* __restrict__ feat, const float* __restrict__ wts,
    float* __restrict__ out)
{
    const int lane = threadIdx.x & 63;
    const int wid  = threadIdx.x >> 6;
    const int gw   = blockIdx.x * 4 + wid;       // 0..2047
    const int iy   = gw >> 4;                    // input row 0..127
    const int ix0  = (gw & 15) * PPW;            // input col base
    const int par  = lane >> 4;                  // 0..3
    const int c4   = lane & 15;                  // channel quad
    const int pi = par >> 1, pj = par & 1;
    const int u = lane & 15;

    float4 w[3][9];
#pragma unroll
    for (int o = 0; o < 3; ++o)
#pragma unroll
        for (int pq = 0; pq < 9; ++pq)
            w[o][pq] = *reinterpret_cast<const float4*>(
                wts + ((par * 3 + o) * 9 + pq) * 64 + c4 * 4);

    for (int g = 0; g < PPW; ++g) {
        const int ix = ix0 + g;
        float acc0 = 0.0f, acc1 = 0.0f, acc2 = 0.0f;
#pragma unroll
        for (int p = 0; p < 3; ++p) {
            const int r = iy + p - 1;
#pragma unroll
            for (int q = 0; q < 3; ++q) {
                const int cc = ix + q - 1;       // wave-uniform
                float4 f;
                if ((unsigned)r < (unsigned)H_IN && (unsigned)cc < (unsigned)W_IN) {
                    f = *reinterpret_cast<const float4*>(
                        feat + (r * W_IN + cc) * C_IN + c4 * 4);
                } else {
                    f = make_float4(0.f, 0.f, 0.f, 0.f);
                }
                const int pq = p * 3 + q;
                acc0 = fmaf(f.x, w[0][pq].x, acc0);
                acc0 = fmaf(f.y, w[0][pq].y, acc0);
                acc0 = fmaf(f.z, w[0][pq].z, acc0);
                acc0 = fmaf(f.w, w[0][pq].w, acc0);
                acc1 = fmaf(f.x, w[1][pq].x, acc1);
                acc1 = fmaf(f.y, w[1][pq].y, acc1);
                acc1 = fmaf(f.z, w[1][pq].z, acc1);
                acc1 = fmaf(f.w, w[1][pq].w, acc1);
                acc2 = fmaf(f.x, w[2][pq].x, acc2);
                acc2 = fmaf(f.y, w[2][pq].y, acc2);
                acc2 = fmaf(f.z, w[2][pq].z, acc2);
                acc2 = fmaf(f.w, w[2][pq].w, acc2);
            }
        }
        // 8-shuffle reduction over 16 lanes for 3 values:
        // (a) xor1/xor2 per acc -> 4-lane-group partials (6 shfl)
        acc0 += __shfl_xor(acc0, 1); acc0 += __shfl_xor(acc0, 2);
        acc1 += __shfl_xor(acc1, 1); acc1 += __shfl_xor(acc1, 2);
        acc2 += __shfl_xor(acc2, 1); acc2 += __shfl_xor(acc2, 2);
        // (b) lane j of each 4-group carries acc_j, reduce across groups (2 shfl)
        const int j = u & 3;
        float v = (j == 0) ? acc0 : ((j == 1) ? acc1 : acc2);
        v += __shfl_xor(v, 4);
        v += __shfl_xor(v, 8);
        if (u < 3) {
            const int oy = 2 * iy + pi;
            const int ox = 2 * ix + pj;
            out[(oy * OUT_W + ox) * OUT_C + u] = v;
        }
    }
}

// ---------------------------------------------------------------------------
extern "C" void kernel_launch(void* const* d_in, const int* in_sizes, int n_in,
                              void* d_out, int out_size, void* d_ws, size_t ws_size,
                              hipStream_t stream)
{
    const float* feat = (const float*)d_in[0];
    const float* k1   = (const float*)d_in[1];
    const float* b1   = (const float*)d_in[2];
    const float* k2   = (const float*)d_in[3];
    const float* b2   = (const float*)d_in[4];
    const float* k3   = (const float*)d_in[5];
    const float* b3   = (const float*)d_in[6];
    float* out = (float*)d_out;
    float* ws  = (float*)d_ws;
    float* wts  = ws;             // 4*1728 floats, [par][o][pq][c]
    float* part = ws + 4 * NW;    // 4*4*256 floats, [par][mc][col]

    mlp12_kernel<<<16, 256, 0, stream>>>(k1, b1, k2, part);
    mlp3_kernel<<<27, 256, 0, stream>>>(k3, b3, b2, part, wts);
    upscale_kernel<<<512, 256, 0, stream>>>(feat, wts, out);
}